// Round 6
// baseline (1042.287 us; speedup 1.0000x reference)
//
#include <hip/hip_runtime.h>
#include <math.h>

#define NROWS 16384
#define DDIM  4096
#define NEXP  64
#define TOPK  8
#define RPW   8            // rows per wave
#define KC    128          // k-chunk staged in LDS (floats per expert)
#define NCH   (DDIM / KC)  // 32 chunks
#define NKB   (KC / 4)     // 32 float4 windows per chunk

// Bit-exact np emulation (verified rounds 3/4):
//  - einsum SSE1: 4 mod-4 fp32 partials, ascending k, separate mul/add
//    rounding (__fmul_rn/__fadd_rn), final (s0+s1)+(s2+s3)
//  - softmax: fp32 max-sub, double-exp->f32, pairwise-8 row sum, IEEE div
//  - top-8 on fp32 probs, ties -> lower index; gates = v/(seq-sum + 1e-9)
//
// Delivery: lane = expert. x rows wave-uniform -> scalar loads (SGPR path,
// proven round 4). W staged per 128-k chunk in LDS, k-major LINEAR layout:
//   Ws[kb][e][0..3] at float index kb*256 + e*4
// Reads AND writes are 1024B-contiguous per wave -> conflict-free, no swizzle.

__global__ __launch_bounds__(256) void router_v6(const float* __restrict__ x,
                                                 const float* __restrict__ W,
                                                 float* __restrict__ out) {
    __shared__ float Ws[NKB * NEXP * 4];   // 32 KB

    const int t    = threadIdx.x;
    const int lane = t & 63;                                  // expert
    const int wv   = __builtin_amdgcn_readfirstlane(t >> 6);  // wave 0..3
    const int row0 = (blockIdx.x * 4 + wv) * RPW;

    const float* xr = x + (size_t)row0 * DDIM;   // wave-uniform base
    const float* wr = W + (size_t)lane * DDIM;   // per-lane expert row

    float s[RPW][4];
    #pragma unroll
    for (int r = 0; r < RPW; ++r)
        #pragma unroll
        for (int p = 0; p < 4; ++p) s[r][p] = 0.f;

    // wave wv stages kb-planes 8*wv .. 8*wv+7; lane covers the expert axis
    float4 wreg[8];
    #pragma unroll
    for (int i = 0; i < 8; ++i)
        wreg[i] = *(const float4*)(wr + (wv * 8 + i) * 4);

    for (int c = 0; c < NCH; ++c) {
        const int k0 = c * KC;

        __syncthreads();               // all waves done reading previous chunk
        #pragma unroll
        for (int i = 0; i < 8; ++i)
            *(float4*)&Ws[((wv * 8 + i) << 8) + (lane << 2)] = wreg[i];
        __syncthreads();               // chunk c visible

        if (c + 1 < NCH) {             // issue next chunk's loads (hide under compute)
            #pragma unroll
            for (int i = 0; i < 8; ++i)
                wreg[i] = *(const float4*)(wr + (k0 + KC) + (wv * 8 + i) * 4);
        }

        // 32 windows of 4 k: 1 ds_read_b128 + 8 uniform x-loads + 64 VALU each
        #pragma unroll
        for (int kb = 0; kb < NKB; ++kb) {
            const float4 w4 = *(const float4*)&Ws[(kb << 8) + (lane << 2)];
            #pragma unroll
            for (int r = 0; r < RPW; ++r) {
                const float4 xv = *(const float4*)(xr + (size_t)r * DDIM + k0 + kb * 4);
                s[r][0] = __fadd_rn(s[r][0], __fmul_rn(xv.x, w4.x));
                s[r][1] = __fadd_rn(s[r][1], __fmul_rn(xv.y, w4.y));
                s[r][2] = __fadd_rn(s[r][2], __fmul_rn(xv.z, w4.z));
                s[r][3] = __fadd_rn(s[r][3], __fmul_rn(xv.w, w4.w));
            }
        }
    }

    // ---- epilogue: per-row softmax + top-k, wave-private (verbatim r4) ----
    float* out_gates = out;
    float* out_idx   = out + (size_t)NROWS * TOPK;
    float* out_probs = out + (size_t)NROWS * TOPK * 2;

    #pragma unroll
    for (int r = 0; r < RPW; ++r) {
        // numpy einsum reduction tree: (s0+s1)+(s2+s3)
        const float l = __fadd_rn(__fadd_rn(s[r][0], s[r][1]),
                                  __fadd_rn(s[r][2], s[r][3]));

        float m = l;
        #pragma unroll
        for (int off = 32; off > 0; off >>= 1)
            m = fmaxf(m, __shfl_xor(m, off));

        const float e = (float)exp((double)__fsub_rn(l, m));

        // numpy pairwise-8 row sum
        const int j8 = lane & 7;
        float rsum = __shfl(e, j8);
        #pragma unroll
        for (int q = 1; q < 8; ++q)
            rsum = __fadd_rn(rsum, __shfl(e, j8 + q * 8));
        const float r0 = __shfl(rsum, 0), r1 = __shfl(rsum, 1);
        const float r2 = __shfl(rsum, 2), r3 = __shfl(rsum, 3);
        const float r4 = __shfl(rsum, 4), r5 = __shfl(rsum, 5);
        const float r6 = __shfl(rsum, 6), r7 = __shfl(rsum, 7);
        const float S = __fadd_rn(__fadd_rn(__fadd_rn(r0, r1), __fadd_rn(r2, r3)),
                                  __fadd_rn(__fadd_rn(r4, r5), __fadd_rn(r6, r7)));

        const float prob = __fdiv_rn(e, S);

        const size_t grow = (size_t)(row0 + r);
        out_probs[grow * NEXP + lane] = prob;

        // top-8 on fp32 probs; ties -> lower index
        float work = prob;
        float myval = 0.f, topsum = 0.f;
        int   myidx = 0;
        for (int it = 0; it < TOPK; ++it) {
            float v = work;
            int   idx = lane;
            #pragma unroll
            for (int off = 32; off > 0; off >>= 1) {
                float ov = __shfl_xor(v, off);
                int   oi = __shfl_xor(idx, off);
                if (ov > v || (ov == v && oi < idx)) { v = ov; idx = oi; }
            }
            const float pw = __shfl(prob, idx);
            topsum = __fadd_rn(topsum, pw);   // rank-order sequential sum
            if (lane == idx) work = -1.0f;    // exclude winner
            if (lane == it)  { myval = pw; myidx = idx; }
        }
        if (lane < TOPK) {
            out_gates[grow * TOPK + lane] = __fdiv_rn(myval, __fadd_rn(topsum, 1e-9f));
            out_idx[grow * TOPK + lane]   = (float)myidx;
        }
    }
}

extern "C" void kernel_launch(void* const* d_in, const int* in_sizes, int n_in,
                              void* d_out, int out_size, void* d_ws, size_t ws_size,
                              hipStream_t stream) {
    const float* x = (const float*)d_in[0];   // (16384, 4096) fp32
    const float* W = (const float*)d_in[1];   // (64, 4096) fp32
    float* out = (float*)d_out;               // gates(N*8) | indices(N*8) | probs(N*64)

    dim3 grid(NROWS / (4 * RPW));  // 512 blocks (4 waves x 8 rows each)
    dim3 block(256);
    hipLaunchKernelGGL(router_v6, grid, block, 0, stream, x, W, out);
}

// Round 8
// 1035.213 us; speedup vs baseline: 1.0068x; 1.0068x over previous
//
#include <hip/hip_runtime.h>
#include <math.h>

#define NROWS 16384
#define DDIM  4096
#define NEXP  64
#define TOPK  8
#define RPW   8            // rows per wave
#define KC    128          // k per LDS chunk
#define NCH   (DDIM / KC)  // 32 chunks
#define NKB   (KC / 4)     // 32 float4 windows per chunk

// Bit-exact np emulation (verified rounds 3/4/6):
//  - einsum SSE1: 4 mod-4 fp32 partials, ascending k, separate mul/add
//    rounding (__fmul_rn/__fadd_rn), final (s0+s1)+(s2+s3)
//  - softmax: fp32 max-sub, double-exp->f32, pairwise-8 row sum, IEEE div
//  - top-8 on fp32 probs, ties -> lower index; gates = v/(seq-sum + 1e-9)
//
// Structure = round 6 EXACTLY (passed): lane = expert; x rows wave-uniform ->
// scalar loads; W reg-staged per 128-k chunk into k-major LINEAR LDS
//   Ws[kb*256 + e*4 .. +3]
// (1024B-contiguous wave reads/writes: conflict-free, no swizzle).
//
// Only change vs round 6: __launch_bounds__(256, 2). Round 6's counters
// (VGPR=68, WRITE_SIZE=349MB vs 5MB real) showed the allocator squeezed the
// fully-unrolled loop into a high-occupancy VGPR cap and spilled everything.
// Grid gives only 2 blocks/CU (2 waves/EU), so declaring that unlocks the
// full register budget at zero occupancy cost. Codegen-only; numerics
// byte-identical to the passing round 6.

__global__ __launch_bounds__(256, 2) void router_v8(const float* __restrict__ x,
                                                    const float* __restrict__ W,
                                                    float* __restrict__ out) {
    __shared__ float Ws[NKB * NEXP * 4];   // 32 KB

    const int t    = threadIdx.x;
    const int lane = t & 63;                                  // expert
    const int wv   = __builtin_amdgcn_readfirstlane(t >> 6);  // wave 0..3
    const int row0 = (blockIdx.x * 4 + wv) * RPW;

    const float* xr = x + (size_t)row0 * DDIM;   // wave-uniform base
    const float* wr = W + (size_t)lane * DDIM;   // per-lane expert row

    float s[RPW][4];
    #pragma unroll
    for (int r = 0; r < RPW; ++r)
        #pragma unroll
        for (int p = 0; p < 4; ++p) s[r][p] = 0.f;

    // wave wv stages kb-planes 8*wv .. 8*wv+7; lane covers the expert axis
    float4 wreg[8];
    #pragma unroll
    for (int i = 0; i < 8; ++i)
        wreg[i] = *(const float4*)(wr + (wv * 8 + i) * 4);

    for (int c = 0; c < NCH; ++c) {
        const int k0 = c * KC;

        __syncthreads();               // all waves done reading previous chunk
        #pragma unroll
        for (int i = 0; i < 8; ++i)
            *(float4*)&Ws[((wv * 8 + i) << 8) + (lane << 2)] = wreg[i];
        __syncthreads();               // chunk c visible

        if (c + 1 < NCH) {             // issue next chunk's loads (hide under compute)
            #pragma unroll
            for (int i = 0; i < 8; ++i)
                wreg[i] = *(const float4*)(wr + (k0 + KC) + (wv * 8 + i) * 4);
        }

        // 32 windows of 4 k: 1 ds_read_b128 + 8 uniform x-loads + 64 VALU each
        #pragma unroll
        for (int kb = 0; kb < NKB; ++kb) {
            const float4 w4 = *(const float4*)&Ws[(kb << 8) + (lane << 2)];
            #pragma unroll
            for (int r = 0; r < RPW; ++r) {
                const float4 xv = *(const float4*)(xr + (size_t)r * DDIM + k0 + kb * 4);
                s[r][0] = __fadd_rn(s[r][0], __fmul_rn(xv.x, w4.x));
                s[r][1] = __fadd_rn(s[r][1], __fmul_rn(xv.y, w4.y));
                s[r][2] = __fadd_rn(s[r][2], __fmul_rn(xv.z, w4.z));
                s[r][3] = __fadd_rn(s[r][3], __fmul_rn(xv.w, w4.w));
            }
        }
    }

    // ---- epilogue: per-row softmax + top-k, wave-private (verbatim r4/r6) ----
    float* out_gates = out;
    float* out_idx   = out + (size_t)NROWS * TOPK;
    float* out_probs = out + (size_t)NROWS * TOPK * 2;

    #pragma unroll
    for (int r = 0; r < RPW; ++r) {
        // numpy einsum reduction tree: (s0+s1)+(s2+s3)
        const float l = __fadd_rn(__fadd_rn(s[r][0], s[r][1]),
                                  __fadd_rn(s[r][2], s[r][3]));

        float m = l;
        #pragma unroll
        for (int off = 32; off > 0; off >>= 1)
            m = fmaxf(m, __shfl_xor(m, off));

        const float e = (float)exp((double)__fsub_rn(l, m));

        // numpy pairwise-8 row sum
        const int j8 = lane & 7;
        float rsum = __shfl(e, j8);
        #pragma unroll
        for (int q = 1; q < 8; ++q)
            rsum = __fadd_rn(rsum, __shfl(e, j8 + q * 8));
        const float r0 = __shfl(rsum, 0), r1 = __shfl(rsum, 1);
        const float r2 = __shfl(rsum, 2), r3 = __shfl(rsum, 3);
        const float r4 = __shfl(rsum, 4), r5 = __shfl(rsum, 5);
        const float r6 = __shfl(rsum, 6), r7 = __shfl(rsum, 7);
        const float S = __fadd_rn(__fadd_rn(__fadd_rn(r0, r1), __fadd_rn(r2, r3)),
                                  __fadd_rn(__fadd_rn(r4, r5), __fadd_rn(r6, r7)));

        const float prob = __fdiv_rn(e, S);

        const size_t grow = (size_t)(row0 + r);
        out_probs[grow * NEXP + lane] = prob;

        // top-8 on fp32 probs; ties -> lower index
        float work = prob;
        float myval = 0.f, topsum = 0.f;
        int   myidx = 0;
        for (int it = 0; it < TOPK; ++it) {
            float v = work;
            int   idx = lane;
            #pragma unroll
            for (int off = 32; off > 0; off >>= 1) {
                float ov = __shfl_xor(v, off);
                int   oi = __shfl_xor(idx, off);
                if (ov > v || (ov == v && oi < idx)) { v = ov; idx = oi; }
            }
            const float pw = __shfl(prob, idx);
            topsum = __fadd_rn(topsum, pw);   // rank-order sequential sum
            if (lane == idx) work = -1.0f;    // exclude winner
            if (lane == it)  { myval = pw; myidx = idx; }
        }
        if (lane < TOPK) {
            out_gates[grow * TOPK + lane] = __fdiv_rn(myval, __fadd_rn(topsum, 1e-9f));
            out_idx[grow * TOPK + lane]   = (float)myidx;
        }
    }
}

extern "C" void kernel_launch(void* const* d_in, const int* in_sizes, int n_in,
                              void* d_out, int out_size, void* d_ws, size_t ws_size,
                              hipStream_t stream) {
    const float* x = (const float*)d_in[0];   // (16384, 4096) fp32
    const float* W = (const float*)d_in[1];   // (64, 4096) fp32
    float* out = (float*)d_out;               // gates(N*8) | indices(N*8) | probs(N*64)

    dim3 grid(NROWS / (4 * RPW));  // 512 blocks (4 waves x 8 rows each)
    dim3 block(256);
    hipLaunchKernelGGL(router_v8, grid, block, 0, stream, x, W, out);
}

// Round 9
// 450.397 us; speedup vs baseline: 2.3142x; 2.2984x over previous
//
#include <hip/hip_runtime.h>
#include <math.h>

#define NROWS 16384
#define DDIM  4096
#define NEXP  64
#define TOPK  8
#define RPW   4            // rows per wave
#define KC    128          // k per LDS chunk
#define NCH   (DDIM / KC)  // 32 chunks
#define NKB   (KC / 4)     // 32 float4 windows per chunk

// Bit-exact np emulation (verified rounds 3/4/6):
//  - einsum SSE1: 4 mod-4 fp32 partials, ascending k, separate mul/add
//    rounding (__fmul_rn/__fadd_rn), final (s0+s1)+(s2+s3)
//  - softmax: fp32 max-sub, double-exp->f32, pairwise-8 row sum, IEEE div
//  - top-8 on fp32 probs, ties -> lower index; gates = v/(seq-sum + 1e-9)
//
// Structure = round 6 skeleton (numerics proven) with two perf changes:
//  1. W staging is TRANSIENT: one float4 temp, load+ds_write between the two
//     barriers, no array held across the compute phase (round 6/8's ~360MB
//     scratch WRITE_SIZE was the register-carried wreg[8] failing promotion;
//     rule #20). Nothing W-related is live across compute.
//  2. RPW 8->4, grid 512->1024 blocks = 4 blocks/CU, 16 waves/CU, so the
//     per-chunk staging latency hides under other blocks' compute.
// W LDS layout unchanged (k-major linear, Ws[kb*256 + e*4]): wave reads and
// writes are 1024B-contiguous -> conflict-free, no swizzle.

__global__ __launch_bounds__(256) void router_v9(const float* __restrict__ x,
                                                 const float* __restrict__ W,
                                                 float* __restrict__ out) {
    __shared__ float Ws[NKB * NEXP * 4];   // 32 KB

    const int t    = threadIdx.x;
    const int lane = t & 63;                                  // expert
    const int wv   = __builtin_amdgcn_readfirstlane(t >> 6);  // wave 0..3
    const int row0 = (blockIdx.x * 4 + wv) * RPW;

    const float* xr = x + (size_t)row0 * DDIM;   // wave-uniform base
    const float* wr = W + (size_t)lane * DDIM;   // per-lane expert row

    float s[RPW][4];
    #pragma unroll
    for (int r = 0; r < RPW; ++r)
        #pragma unroll
        for (int p = 0; p < 4; ++p) s[r][p] = 0.f;

    for (int c = 0; c < NCH; ++c) {
        const int k0 = c * KC;

        // ---- stage W chunk c (transient temps only) ----
        __syncthreads();               // all waves done reading previous chunk
        #pragma unroll
        for (int i = 0; i < 8; ++i) {
            const int kb = wv * 8 + i;              // this wave's kb planes
            const float4 wtmp = *(const float4*)(wr + k0 + kb * 4);
            *(float4*)&Ws[(kb << 8) + (lane << 2)] = wtmp;
        }
        __syncthreads();               // chunk c visible

        // ---- compute: 32 windows of 4k; 1 ds_read_b128 + scalar x-loads ----
        #pragma unroll
        for (int kb = 0; kb < NKB; ++kb) {
            const float4 w4 = *(const float4*)&Ws[(kb << 8) + (lane << 2)];
            #pragma unroll
            for (int r = 0; r < RPW; ++r) {
                const float4 xv = *(const float4*)(xr + (size_t)r * DDIM + k0 + kb * 4);
                s[r][0] = __fadd_rn(s[r][0], __fmul_rn(xv.x, w4.x));
                s[r][1] = __fadd_rn(s[r][1], __fmul_rn(xv.y, w4.y));
                s[r][2] = __fadd_rn(s[r][2], __fmul_rn(xv.z, w4.z));
                s[r][3] = __fadd_rn(s[r][3], __fmul_rn(xv.w, w4.w));
            }
        }
    }

    // ---- epilogue: per-row softmax + top-k, wave-private (verbatim r4/r6) ----
    float* out_gates = out;
    float* out_idx   = out + (size_t)NROWS * TOPK;
    float* out_probs = out + (size_t)NROWS * TOPK * 2;

    #pragma unroll
    for (int r = 0; r < RPW; ++r) {
        // numpy einsum reduction tree: (s0+s1)+(s2+s3)
        const float l = __fadd_rn(__fadd_rn(s[r][0], s[r][1]),
                                  __fadd_rn(s[r][2], s[r][3]));

        float m = l;
        #pragma unroll
        for (int off = 32; off > 0; off >>= 1)
            m = fmaxf(m, __shfl_xor(m, off));

        const float e = (float)exp((double)__fsub_rn(l, m));

        // numpy pairwise-8 row sum
        const int j8 = lane & 7;
        float rsum = __shfl(e, j8);
        #pragma unroll
        for (int q = 1; q < 8; ++q)
            rsum = __fadd_rn(rsum, __shfl(e, j8 + q * 8));
        const float r0 = __shfl(rsum, 0), r1 = __shfl(rsum, 1);
        const float r2 = __shfl(rsum, 2), r3 = __shfl(rsum, 3);
        const float r4 = __shfl(rsum, 4), r5 = __shfl(rsum, 5);
        const float r6 = __shfl(rsum, 6), r7 = __shfl(rsum, 7);
        const float S = __fadd_rn(__fadd_rn(__fadd_rn(r0, r1), __fadd_rn(r2, r3)),
                                  __fadd_rn(__fadd_rn(r4, r5), __fadd_rn(r6, r7)));

        const float prob = __fdiv_rn(e, S);

        const size_t grow = (size_t)(row0 + r);
        out_probs[grow * NEXP + lane] = prob;

        // top-8 on fp32 probs; ties -> lower index
        float work = prob;
        float myval = 0.f, topsum = 0.f;
        int   myidx = 0;
        for (int it = 0; it < TOPK; ++it) {
            float v = work;
            int   idx = lane;
            #pragma unroll
            for (int off = 32; off > 0; off >>= 1) {
                float ov = __shfl_xor(v, off);
                int   oi = __shfl_xor(idx, off);
                if (ov > v || (ov == v && oi < idx)) { v = ov; idx = oi; }
            }
            const float pw = __shfl(prob, idx);
            topsum = __fadd_rn(topsum, pw);   // rank-order sequential sum
            if (lane == idx) work = -1.0f;    // exclude winner
            if (lane == it)  { myval = pw; myidx = idx; }
        }
        if (lane < TOPK) {
            out_gates[grow * TOPK + lane] = __fdiv_rn(myval, __fadd_rn(topsum, 1e-9f));
            out_idx[grow * TOPK + lane]   = (float)myidx;
        }
    }
}

extern "C" void kernel_launch(void* const* d_in, const int* in_sizes, int n_in,
                              void* d_out, int out_size, void* d_ws, size_t ws_size,
                              hipStream_t stream) {
    const float* x = (const float*)d_in[0];   // (16384, 4096) fp32
    const float* W = (const float*)d_in[1];   // (64, 4096) fp32
    float* out = (float*)d_out;               // gates(N*8) | indices(N*8) | probs(N*64)

    dim3 grid(NROWS / (4 * RPW));  // 1024 blocks (4 waves x 4 rows each)
    dim3 block(256);
    hipLaunchKernelGGL(router_v9, grid, block, 0, stream, x, W, out);
}